// Round 14
// baseline (1267.454 us; speedup 1.0000x reference)
//
#include <hip/hip_runtime.h>

typedef _Float16 half8 __attribute__((ext_vector_type(8)));
typedef _Float16 half4 __attribute__((ext_vector_type(4)));
typedef float f32x4 __attribute__((ext_vector_type(4)));
typedef unsigned int u32x2 __attribute__((ext_vector_type(2)));

#define B_SZ   2048
#define T_SZ   128
#define IN_SZ  64
#define H_SZ   256
#define G4     1024
#define NB     8        // col-blocks per group
#define NG16   128      // 16-row batch groups
#define NTHR   1024     // 16 waves = 8 chains x 2 waves
#define KT_N   10
#define FTGT   16       // flag target: 8 blocks x 2 waves per group

__device__ __forceinline__ float sigmoidf_(float x) { return 1.0f / (1.0f + __expf(-x)); }
__device__ __forceinline__ float tanhf_(float x) { return 1.0f - 2.0f / (__expf(2.0f * x) + 1.0f); }

// Repack W -> fp16, tile/fragment-ordered for the SWAPPED GEMM (A = W).
// Tile TI = nbk*8 + sub. Tile row m (q = m&3, cs = m>>2) maps to orig gate row
//   grow = q*256 + nbk*32 + (sub>>2)*16 + cs*4 + (sub&3)
// so a lane's 4 acc tiles (ti) cover 4 CONTIGUOUS h-cols. (Verified R13.)
__global__ void prep_kernel(const float* __restrict__ W_ih, const float* __restrict__ W_hh,
                            const float* __restrict__ b_ih, const float* __restrict__ b_hh,
                            _Float16* __restrict__ Wr, float* __restrict__ biasr) {
  const int tid = blockIdx.x * blockDim.x + threadIdx.x;   // 0..40959
  if (tid < G4) {
    const int TI = tid >> 4, m = tid & 15;
    const int q = m & 3, cs = m >> 2, nbk = TI >> 3, sub = TI & 7;
    const int grow = q * 256 + nbk * 32 + (sub >> 2) * 16 + cs * 4 + (sub & 3);
    biasr[tid] = b_ih[grow] + b_hh[grow];
  }
  if (tid >= 64 * KT_N * 64) return;
  const int l = tid & 63, kt = (tid >> 6) % KT_N, TI = tid / (64 * KT_N);
  const int lm = l & 15, lk = l >> 4;
  const int q = lm & 3, cs = lm >> 2, nbk = TI >> 3, sub = TI & 7;
  const int grow = q * 256 + nbk * 32 + (sub >> 2) * 16 + cs * 4 + (sub & 3);
  const int k0 = kt * 32 + lk * 8;
  _Float16 v[8];
  #pragma unroll
  for (int kk = 0; kk < 8; ++kk) {
    const int k = k0 + kk;
    v[kk] = (_Float16)((k < IN_SZ) ? W_ih[grow * IN_SZ + k] : W_hh[grow * H_SZ + k - IN_SZ]);
  }
  *(half8*)&Wr[((size_t)(TI * KT_N + kt) * 64 + l) * 8] = *(half8*)v;
}

// Persistent recurrence: W LDS-resident, 8 autonomous chains (16 rows) per block,
// NO in-loop barriers. Per-wave flag increments; all-lane spin; sc0 sc1 exchange.
__global__ __launch_bounds__(NTHR, 4)
void lstm_kernel(const float* __restrict__ x,
                 const _Float16* __restrict__ Wr,
                 const float* __restrict__ biasr,
                 const float* __restrict__ fcW,
                 _Float16* __restrict__ hbuf,
                 int* __restrict__ flags,
                 float* __restrict__ partial) {
  __shared__ __align__(16) char smem[81920];               // Wlds; reused for FC
  _Float16* Wlds = (_Float16*)smem;

  const int tid = threadIdx.x;
  const int l = tid & 63;
  const int w = tid >> 6;                  // wave 0..15
  const int lm = l & 15, lk = l >> 4;
  const int chain = w >> 1, gh = w & 1;    // 8 chains x 2 gate-half waves
  const int gp = blockIdx.x >> 3, nbk = blockIdx.x & 7;
  const int g16 = gp * 8 + chain;          // 16-row batch group id
  const int brow = g16 * 16 + lm;          // this lane's batch row

  // stage this block's W slice: 8 subs x 10 kt x 512 halves = 80 KB
  #pragma unroll
  for (int rep = 0; rep < 5; ++rep) {
    const int u = rep * NTHR + tid;        // 0..5119 half8 units
    const int sub = u / 640, r2 = u % 640, kt = r2 >> 6, l2 = r2 & 63;
    *(half8*)&Wlds[((size_t)(sub * KT_N + kt) * 64 + l2) * 8] =
        *(const half8*)&Wr[(((size_t)(nbk * 8 + sub) * KT_N + kt) * 64 + l2) * 8];
  }

  f32x4 bias[4];
  #pragma unroll
  for (int ti = 0; ti < 4; ++ti)
    bias[ti] = *(const f32x4*)&biasr[(nbk * 8 + gh * 4 + ti) * 16 + lk * 4];

  const float* xlane = x + (size_t)brow * T_SZ * IN_SZ + lk * 8;
  const int colb = gh * 16 + lk * 4;       // block-local h-col base (+ ti)
  int* flagg = flags + g16 * T_SZ;

  __syncthreads();   // Wlds ready (only barrier before FC tail)

  float cst[4] = {0.f, 0.f, 0.f, 0.f};
  float hvf[4] = {0.f, 0.f, 0.f, 0.f};

  #define WL(ti_, kt_) (*(const half8*)&Wlds[((size_t)((gh * 4 + (ti_)) * KT_N + (kt_)) * 64 + l) * 8])

  // prologue: x_0 -> bx
  half8 bx0, bx1;
  {
    const float* xp = xlane;
    const f32x4 a0 = *(const f32x4*)(xp);
    const f32x4 a1 = *(const f32x4*)(xp + 4);
    const f32x4 b0 = *(const f32x4*)(xp + 32);
    const f32x4 b1 = *(const f32x4*)(xp + 36);
    #pragma unroll
    for (int i = 0; i < 4; ++i) {
      bx0[i] = (_Float16)a0[i]; bx0[4 + i] = (_Float16)a1[i];
      bx1[i] = (_Float16)b0[i]; bx1[4 + i] = (_Float16)b1[i];
    }
  }

  for (int t = 0; t < T_SZ; ++t) {
    const int par = t & 1;
    const bool hx = (t + 1 < T_SZ);

    f32x4 acc[4];
    #pragma unroll
    for (int ti = 0; ti < 4; ++ti) acc[ti] = bias[ti];

    // x-part MFMAs (kt 0,1) — bx ready from last step
    #pragma unroll
    for (int ti = 0; ti < 4; ++ti)
      acc[ti] = __builtin_amdgcn_mfma_f32_16x16x32_f16(WL(ti, 0), bx0, acc[ti], 0, 0, 0);
    #pragma unroll
    for (int ti = 0; ti < 4; ++ti)
      acc[ti] = __builtin_amdgcn_mfma_f32_16x16x32_f16(WL(ti, 1), bx1, acc[ti], 0, 0, 0);

    // cross-step x prefetch
    f32x4 xa0, xa1, xb0, xb1;
    if (hx) {
      const float* xp = xlane + (t + 1) * IN_SZ;
      xa0 = *(const f32x4*)(xp);
      xa1 = *(const f32x4*)(xp + 4);
      xb0 = *(const f32x4*)(xp + 32);
      xb1 = *(const f32x4*)(xp + 36);
      asm volatile("" : "+v"(xa0), "+v"(xa1), "+v"(xb0), "+v"(xb1));
    }

    if (t > 0) {
      // all-lane spin on this chain's group flag (uniform address)
      while (__hip_atomic_load(flagg + (t - 1), __ATOMIC_RELAXED, __HIP_MEMORY_SCOPE_AGENT) < FTGT)
        __builtin_amdgcn_s_sleep(1);

      // coherent h loads (sc0 sc1)
      const char* hb = (const char*)hbuf + (size_t)(par ^ 1) * (B_SZ * H_SZ * 2)
                       + (size_t)brow * (H_SZ * 2) + lk * 16;
      f32x4 hr0, hr1, hr2, hr3, hr4, hr5, hr6, hr7;
      asm volatile("global_load_dwordx4 %0, %1, off sc0 sc1"            : "=v"(hr0) : "v"(hb));
      asm volatile("global_load_dwordx4 %0, %1, off offset:64 sc0 sc1"  : "=v"(hr1) : "v"(hb));
      asm volatile("global_load_dwordx4 %0, %1, off offset:128 sc0 sc1" : "=v"(hr2) : "v"(hb));
      asm volatile("global_load_dwordx4 %0, %1, off offset:192 sc0 sc1" : "=v"(hr3) : "v"(hb));
      asm volatile("global_load_dwordx4 %0, %1, off offset:256 sc0 sc1" : "=v"(hr4) : "v"(hb));
      asm volatile("global_load_dwordx4 %0, %1, off offset:320 sc0 sc1" : "=v"(hr5) : "v"(hb));
      asm volatile("global_load_dwordx4 %0, %1, off offset:384 sc0 sc1" : "=v"(hr6) : "v"(hb));
      asm volatile("global_load_dwordx4 %0, %1, off offset:448 sc0 sc1" : "=v"(hr7) : "v"(hb));
      asm volatile("s_waitcnt vmcnt(0)"
                   : "+v"(hr0), "+v"(hr1), "+v"(hr2), "+v"(hr3),
                     "+v"(hr4), "+v"(hr5), "+v"(hr6), "+v"(hr7));
      __builtin_amdgcn_sched_barrier(0);

      #define HMK(kk_, hr_) { const half8 hh = __builtin_bit_cast(half8, hr_); \
        _Pragma("unroll") \
        for (int ti = 0; ti < 4; ++ti) \
          acc[ti] = __builtin_amdgcn_mfma_f32_16x16x32_f16(WL(ti, 2 + kk_), hh, acc[ti], 0, 0, 0); }
      HMK(0, hr0) HMK(1, hr1) HMK(2, hr2) HMK(3, hr3)
      HMK(4, hr4) HMK(5, hr5) HMK(6, hr6) HMK(7, hr7)
      #undef HMK
    }

    // convert prefetched x for next step
    if (hx) {
      #pragma unroll
      for (int i = 0; i < 4; ++i) {
        bx0[i] = (_Float16)xa0[i]; bx0[4 + i] = (_Float16)xa1[i];
        bx1[i] = (_Float16)xb0[i]; bx1[4 + i] = (_Float16)xb1[i];
      }
    }

    // cell update: acc[ti][q] = gate q for h-col colb+ti (contiguous), batch brow
    half4 hv4;
    #pragma unroll
    for (int ti = 0; ti < 4; ++ti) {
      const float iv = sigmoidf_(acc[ti][0]);
      const float fv = sigmoidf_(acc[ti][1]);
      const float gv = tanhf_   (acc[ti][2]);
      const float ov = sigmoidf_(acc[ti][3]);
      const float cn = fv * cst[ti] + iv * gv;
      cst[ti] = cn;
      const float hv = ov * tanhf_(cn);
      hvf[ti] = hv;
      hv4[ti] = (_Float16)hv;
    }

    if (hx) {
      char* dst = (char*)hbuf + (size_t)par * (B_SZ * H_SZ * 2)
                  + ((size_t)brow * H_SZ + nbk * 32 + colb) * 2;
      const u32x2 val = __builtin_bit_cast(u32x2, hv4);
      asm volatile("global_store_dwordx2 %0, %1, off sc0 sc1" :: "v"(dst), "v"(val) : "memory");
      asm volatile("s_waitcnt vmcnt(0)" ::: "memory");   // own store visible
      if (l == 0)
        __hip_atomic_fetch_add(flagg + t, 1, __ATOMIC_RELAXED, __HIP_MEMORY_SCOPE_AGENT);
    }
  }
  #undef WL

  // FC tail: partial[b] over this block's 32 cols (reuse smem after all loops done)
  __syncthreads();
  float* fcred = (float*)smem;   // [8 chains][16 rows][2 gh]
  float p = 0.f;
  #pragma unroll
  for (int ti = 0; ti < 4; ++ti)
    p += hvf[ti] * fcW[nbk * 32 + colb + ti];
  p += __shfl_xor(p, 16);
  p += __shfl_xor(p, 32);
  if (lk == 0) fcred[(chain * 16 + lm) * 2 + gh] = p;
  __syncthreads();
  if (tid < 128) {
    const int c2 = tid >> 4, r2 = tid & 15;
    partial[(size_t)nbk * B_SZ + (gp * 8 + c2) * 16 + r2] =
        fcred[(c2 * 16 + r2) * 2 + 0] + fcred[(c2 * 16 + r2) * 2 + 1];
  }
}

__global__ void fc_kernel(const float* __restrict__ partial, const float* __restrict__ fcb,
                          float* __restrict__ out) {
  const int b = blockIdx.x * 256 + threadIdx.x;
  if (b >= B_SZ) return;
  float s = fcb[0];
  #pragma unroll
  for (int n = 0; n < NB; ++n) s += partial[(size_t)n * B_SZ + b];
  out[b] = s;
}

extern "C" void kernel_launch(void* const* d_in, const int* in_sizes, int n_in,
                              void* d_out, int out_size, void* d_ws, size_t ws_size,
                              hipStream_t stream) {
  const float* x    = (const float*)d_in[0];
  const float* W_ih = (const float*)d_in[1];
  const float* W_hh = (const float*)d_in[2];
  const float* b_ih = (const float*)d_in[3];
  const float* b_hh = (const float*)d_in[4];
  const float* fcW  = (const float*)d_in[5];
  const float* fcb  = (const float*)d_in[6];
  float* out = (float*)d_out;

  // ws: Wr 655360 | biasr 4096 | hbuf 2MB | flags 64KB | partial 64KB
  char* ws = (char*)d_ws;
  _Float16* Wr   = (_Float16*)ws;
  float* biasr   = (float*)(ws + 655360);
  _Float16* hbuf = (_Float16*)(ws + 659456);
  int* flags     = (int*)(ws + 659456 + 2097152);
  float* partial = (float*)(ws + 659456 + 2097152 + 65536);

  hipMemsetAsync(flags, 0, NG16 * T_SZ * sizeof(int), stream);
  hipLaunchKernelGGL(prep_kernel, dim3(160), dim3(256), 0, stream,
                     W_ih, W_hh, b_ih, b_hh, Wr, biasr);
  hipLaunchKernelGGL(lstm_kernel, dim3(128), dim3(NTHR), 0, stream,
                     x, Wr, biasr, fcW, hbuf, flags, partial);
  hipLaunchKernelGGL(fc_kernel, dim3(8), dim3(256), 0, stream,
                     partial, fcb, out);
}